// Round 2
// baseline (635.680 us; speedup 1.0000x reference)
//
#include <hip/hip_runtime.h>
#include <hip/hip_bf16.h>

#define NPX 16384   // H*W
using bf16 = __hip_bfloat16;

static __device__ __forceinline__ float lrelu(float v) { return v >= 0.f ? v : 0.01f * v; }
static __device__ __forceinline__ float ldv(const float* p) { return *p; }
static __device__ __forceinline__ float ldv(const bf16* p) { return __bfloat162float(*p); }

// ---------------------------------------------------------------------------
// Streamed per-pixel GEMM: acc[e] += sum_c in[c*NPX] * w[c*COUT+e]
// Weights read with wave-uniform addresses -> compiler emits s_load (SMEM),
// inner loop is v_fmac_f32 with SGPR operand. Input double-buffered 8-deep.
// ---------------------------------------------------------------------------
template<int CIN, int COUT, typename T>
static __device__ __forceinline__ void gemm_px(const T* __restrict__ ip,
                                               const float* __restrict__ w,
                                               float* acc)
{
    float cur[8], nxt[8];
#pragma unroll
    for (int j = 0; j < 8; ++j) cur[j] = ldv(ip + j * NPX);
#pragma unroll 1
    for (int c0 = 0; c0 < CIN; c0 += 8) {
        if (c0 + 8 < CIN) {
#pragma unroll
            for (int j = 0; j < 8; ++j) nxt[j] = ldv(ip + (c0 + 8 + j) * NPX);
        }
#pragma unroll
        for (int j = 0; j < 8; ++j) {
            const float* wr = w + (c0 + j) * COUT;   // uniform address
#pragma unroll
            for (int e = 0; e < COUT; ++e) acc[e] = fmaf(cur[j], wr[e], acc[e]);
        }
#pragma unroll
        for (int j = 0; j < 8; ++j) cur[j] = nxt[j];
    }
}

// weight accessor for the per-class feature matmul (j unrolled -> constants)
static __device__ __forceinline__ float wfeat(const float* __restrict__ wa,
                                              const float* __restrict__ wb,
                                              int c, int j)
{
    return (j < 4) ? wa[c * 4 + j]
                   : wb[((j - 4) / 3) * 192 + c * 3 + ((j - 4) % 3)];
}

// ---------------------------------------------------------------------------
// K1: x,sem -> y = (concat-feat) @ in_w + in_b   (feat stays in registers)
// ---------------------------------------------------------------------------
__global__ __launch_bounds__(256) void k_fused_y(const float* __restrict__ x,
                                                 const float* __restrict__ sem,
                                                 const float* __restrict__ wa,
                                                 const float* __restrict__ ba,
                                                 const float* __restrict__ wb,
                                                 const float* __restrict__ bbv,
                                                 const float* __restrict__ in_w,
                                                 const float* __restrict__ in_b,
                                                 bf16* __restrict__ y)
{
    int gid = blockIdx.x * 256 + threadIdx.x;
    int b = gid >> 14, n = gid & (NPX - 1);
    const float* xp = x + (size_t)b * 64 * NPX + n;

    float acc[64];
#pragma unroll
    for (int j = 0; j < 64; ++j) acc[j] = 0.f;

    float cur[8], nxt[8];
#pragma unroll
    for (int j = 0; j < 8; ++j) cur[j] = xp[j * NPX];
#pragma unroll 1
    for (int c0 = 0; c0 < 64; c0 += 8) {
        if (c0 + 8 < 64) {
#pragma unroll
            for (int j = 0; j < 8; ++j) nxt[j] = xp[(c0 + 8 + j) * NPX];
        }
#pragma unroll
        for (int j = 0; j < 8; ++j) {
            int c = c0 + j;
#pragma unroll
            for (int jj = 0; jj < 64; ++jj)
                acc[jj] = fmaf(cur[j], wfeat(wa, wb, c, jj), acc[jj]);
        }
#pragma unroll
        for (int j = 0; j < 8; ++j) cur[j] = nxt[j];
    }

    float sm[21];
    const float* sp = sem + (size_t)b * 21 * NPX + n;
#pragma unroll
    for (int kk = 0; kk < 21; ++kk) sm[kk] = fmaxf(sp[kk * NPX], 0.f);

    float yv[64];
#pragma unroll
    for (int e = 0; e < 64; ++e) yv[e] = in_b[e];
#pragma unroll
    for (int j = 0; j < 64; ++j) {
        const int cls = (j < 4) ? 0 : 1 + (j - 4) / 3;
        float bias = (j < 4) ? ba[j] : bbv[j - 4];
        float fj = sm[cls] * acc[j] + bias;
#pragma unroll
        for (int e = 0; e < 64; ++e) yv[e] = fmaf(fj, in_w[j * 64 + e], yv[e]);
    }
    bf16* yp = y + (size_t)b * 64 * NPX + n;
#pragma unroll
    for (int e = 0; e < 64; ++e) yp[e * NPX] = __float2bfloat16(yv[e]);
}

// ---------------------------------------------------------------------------
// K2: h1n = lrelu(LN(x @ w1 + b1))   64 -> 128, bf16 out
// ---------------------------------------------------------------------------
__global__ __launch_bounds__(256) void k_mlp1(const float* __restrict__ x,
                                              const float* __restrict__ w1,
                                              const float* __restrict__ b1,
                                              const float* __restrict__ g1,
                                              const float* __restrict__ be1,
                                              bf16* __restrict__ h1n)
{
    int gid = blockIdx.x * 256 + threadIdx.x;
    int b = gid >> 14, n = gid & (NPX - 1);
    const float* xp = x + (size_t)b * 64 * NPX + n;
    float acc[128];
#pragma unroll
    for (int d = 0; d < 128; ++d) acc[d] = b1[d];
    gemm_px<64, 128, float>(xp, w1, acc);
    float mean = 0.f;
#pragma unroll
    for (int d = 0; d < 128; ++d) mean += acc[d];
    mean *= (1.f / 128.f);
    float var = 0.f;
#pragma unroll
    for (int d = 0; d < 128; ++d) { float t = acc[d] - mean; var += t * t; }
    float rs = rsqrtf(var * (1.f / 128.f) + 1e-5f);
    bf16* op = h1n + (size_t)b * 128 * NPX + n;
#pragma unroll
    for (int d = 0; d < 128; ++d)
        op[d * NPX] = __float2bfloat16(lrelu((acc[d] - mean) * rs * g1[d] + be1[d]));
}

// ---------------------------------------------------------------------------
// K3: h2n = lrelu(LN(h1n @ w2 + b2))   128 -> 128, bf16
// ---------------------------------------------------------------------------
__global__ __launch_bounds__(256) void k_mlp2(const bf16* __restrict__ h1n,
                                              const float* __restrict__ w2,
                                              const float* __restrict__ b2,
                                              const float* __restrict__ g2,
                                              const float* __restrict__ be2,
                                              bf16* __restrict__ h2n)
{
    int gid = blockIdx.x * 256 + threadIdx.x;
    int b = gid >> 14, n = gid & (NPX - 1);
    const bf16* ip = h1n + (size_t)b * 128 * NPX + n;
    float acc[128];
#pragma unroll
    for (int d = 0; d < 128; ++d) acc[d] = b2[d];
    gemm_px<128, 128, bf16>(ip, w2, acc);
    float mean = 0.f;
#pragma unroll
    for (int d = 0; d < 128; ++d) mean += acc[d];
    mean *= (1.f / 128.f);
    float var = 0.f;
#pragma unroll
    for (int d = 0; d < 128; ++d) { float t = acc[d] - mean; var += t * t; }
    float rs = rsqrtf(var * (1.f / 128.f) + 1e-5f);
    bf16* op = h2n + (size_t)b * 128 * NPX + n;
#pragma unroll
    for (int d = 0; d < 128; ++d)
        op[d * NPX] = __float2bfloat16(lrelu((acc[d] - mean) * rs * g2[d] + be2[d]));
}

// ---------------------------------------------------------------------------
// K4: xm = h2n @ w3 + b3 (fp32 out, needed for residual); q = xm @ wq + bq (bf16)
// ---------------------------------------------------------------------------
__global__ __launch_bounds__(256) void k_mlp3q(const bf16* __restrict__ h2n,
                                               const float* __restrict__ w3,
                                               const float* __restrict__ b3,
                                               const float* __restrict__ wq,
                                               const float* __restrict__ bq,
                                               float* __restrict__ xm,
                                               bf16* __restrict__ q)
{
    int gid = blockIdx.x * 256 + threadIdx.x;
    int b = gid >> 14, n = gid & (NPX - 1);
    const bf16* ip = h2n + (size_t)b * 128 * NPX + n;
    float acc[64];
#pragma unroll
    for (int e = 0; e < 64; ++e) acc[e] = b3[e];
    gemm_px<128, 64, bf16>(ip, w3, acc);
    float* xp = xm + (size_t)b * 64 * NPX + n;
#pragma unroll
    for (int e = 0; e < 64; ++e) xp[e * NPX] = acc[e];

    float qv[64];
#pragma unroll
    for (int e = 0; e < 64; ++e) qv[e] = bq[e];
#pragma unroll
    for (int j = 0; j < 64; ++j) {
#pragma unroll
        for (int e = 0; e < 64; ++e) qv[e] = fmaf(acc[j], wq[j * 64 + e], qv[e]);
    }
    bf16* qp = q + (size_t)b * 64 * NPX + n;
#pragma unroll
    for (int e = 0; e < 64; ++e) qp[e * NPX] = __float2bfloat16(qv[e]);
}

// ---------------------------------------------------------------------------
// K5: k = y @ wk + bk,  v = y @ wv + bv   (both bf16)
// ---------------------------------------------------------------------------
__global__ __launch_bounds__(256) void k_kv(const bf16* __restrict__ y,
                                            const float* __restrict__ wk,
                                            const float* __restrict__ bk,
                                            const float* __restrict__ wv,
                                            const float* __restrict__ bv,
                                            bf16* __restrict__ kko,
                                            bf16* __restrict__ vvo)
{
    int gid = blockIdx.x * 256 + threadIdx.x;
    int b = gid >> 14, n = gid & (NPX - 1);
    const bf16* ip = y + (size_t)b * 64 * NPX + n;
    float acc[64];
#pragma unroll
    for (int e = 0; e < 64; ++e) acc[e] = bk[e];
    gemm_px<64, 64, bf16>(ip, wk, acc);
    bf16* kp = kko + (size_t)b * 64 * NPX + n;
#pragma unroll
    for (int e = 0; e < 64; ++e) kp[e * NPX] = __float2bfloat16(acc[e]);

#pragma unroll
    for (int e = 0; e < 64; ++e) acc[e] = bv[e];
    gemm_px<64, 64, bf16>(ip, wv, acc);
    bf16* vp = vvo + (size_t)b * 64 * NPX + n;
#pragma unroll
    for (int e = 0; e < 64; ++e) vp[e * NPX] = __float2bfloat16(acc[e]);
}

// ---------------------------------------------------------------------------
// K6: gram[b,h,d,e] += sum_n q*k ; nsq (q,k row sum-sq) — LDS-tiled, atomics
// grid: 256 blocks = 16 (b,h) x 16 chunks of 1024 px
// ---------------------------------------------------------------------------
__global__ __launch_bounds__(256) void k_gramnorm(const bf16* __restrict__ q,
                                                  const bf16* __restrict__ kk,
                                                  float* __restrict__ gram,
                                                  float* __restrict__ nsq)
{
    __shared__ float qs[16 * 257], ks[16 * 257];
    int bh = blockIdx.x >> 4;             // b*4+h
    int b = bh >> 2, h = bh & 3;
    int n0 = (blockIdx.x & 15) * 1024;
    int tid = threadIdx.x;
    int d = tid >> 4, e = tid & 15;
    const bf16* qb = q + ((size_t)b * 64 + h * 16) * NPX;
    const bf16* kb = kk + ((size_t)b * 64 + h * 16) * NPX;

    float s = 0.f, sq = 0.f, sk = 0.f;
    for (int sub = 0; sub < 4; ++sub) {
        int nb = n0 + sub * 256;
        __syncthreads();
        int row = tid >> 4, col0 = tid & 15;
#pragma unroll
        for (int jj = 0; jj < 16; ++jj) {
            int px = col0 + jj * 16;
            qs[row * 257 + px] = __bfloat162float(qb[(size_t)row * NPX + nb + px]);
            ks[row * 257 + px] = __bfloat162float(kb[(size_t)row * NPX + nb + px]);
        }
        __syncthreads();
#pragma unroll 8
        for (int i = 0; i < 256; ++i) {
            float qv = qs[d * 257 + i], kv = ks[e * 257 + i];
            s = fmaf(qv, kv, s);
            if (e == 0) sq = fmaf(qv, qv, sq);
            if (d == 0) sk = fmaf(kv, kv, sk);
        }
    }
    atomicAdd(gram + bh * 256 + d * 16 + e, s);
    if (e == 0) atomicAdd(nsq + bh * 16 + d, sq);
    if (d == 0) atomicAdd(nsq + 256 + bh * 16 + e, sk);
}

// ---------------------------------------------------------------------------
// K7: per-batch M[he][cc] = sum_d softmax(logits)[h,d,e] * wo[(h*16+d)*64+cc]
// grid: 4 blocks (one per batch)
// ---------------------------------------------------------------------------
__global__ __launch_bounds__(256) void k_attnM(const float* __restrict__ gram,
                                               const float* __restrict__ nsq,
                                               const float* __restrict__ rescale,
                                               const float* __restrict__ wo,
                                               float* __restrict__ M)
{
    __shared__ float s_at[1024];
    int b = blockIdx.x, tid = threadIdx.x;
    if (tid < 64) {
        int h = tid >> 4, d = tid & 15;
        float nq = sqrtf(nsq[b * 64 + h * 16 + d]) + 1e-8f;
        float rsc = rescale[h];
        float lg[16];
#pragma unroll
        for (int e = 0; e < 16; ++e) {
            float nk = sqrtf(nsq[256 + b * 64 + h * 16 + e]) + 1e-8f;
            lg[e] = rsc * gram[b * 1024 + h * 256 + d * 16 + e] / (nq * nk);
        }
        float m = lg[0];
#pragma unroll
        for (int e = 1; e < 16; ++e) m = fmaxf(m, lg[e]);
        float ssum = 0.f;
#pragma unroll
        for (int e = 0; e < 16; ++e) { lg[e] = expf(lg[e] - m); ssum += lg[e]; }
        float inv = 1.f / ssum;
#pragma unroll
        for (int e = 0; e < 16; ++e) s_at[h * 256 + d * 16 + e] = lg[e] * inv;
    }
    __syncthreads();
    int he = tid >> 2;                   // 0..63
    int h = he >> 4, e = he & 15;
    int cc0 = (tid & 3) * 16;
#pragma unroll
    for (int cx = 0; cx < 16; ++cx) {
        int cc = cc0 + cx;
        float s = 0.f;
#pragma unroll
        for (int d = 0; d < 16; ++d)
            s = fmaf(s_at[h * 256 + d * 16 + e], wo[(h * 16 + d) * 64 + cc], s);
        M[b * 4096 + he * 64 + cc] = s;
    }
}

// ---------------------------------------------------------------------------
// K8: out[b,cc,n] = sum_he v[b,he,n]*M[b][he][cc] + bo[cc] + xm[b,cc,n]
// ---------------------------------------------------------------------------
__global__ __launch_bounds__(256) void k_out(const bf16* __restrict__ v,
                                             const float* __restrict__ xm,
                                             const float* __restrict__ M,
                                             const float* __restrict__ bo,
                                             float* __restrict__ out)
{
    int gid = blockIdx.x * 256 + threadIdx.x;
    int b = gid >> 14, n = gid & (NPX - 1);
    const bf16* vp = v + (size_t)b * 64 * NPX + n;
    const float* Mb = M + b * 4096;       // uniform per block
    float acc[64];
#pragma unroll
    for (int e = 0; e < 64; ++e) acc[e] = bo[e];
    gemm_px<64, 64, bf16>(vp, Mb, acc);
    const float* xp = xm + (size_t)b * 64 * NPX + n;
    float* op = out + (size_t)b * 64 * NPX + n;
#pragma unroll
    for (int e = 0; e < 64; ++e) op[e * NPX] = acc[e] + xp[e * NPX];
}

// ---------------------------------------------------------------------------
extern "C" void kernel_launch(void* const* d_in, const int* in_sizes, int n_in,
                              void* d_out, int out_size, void* d_ws, size_t ws_size,
                              hipStream_t stream)
{
    const float* x    = (const float*)d_in[0];
    const float* sem  = (const float*)d_in[1];
    const float* wa   = (const float*)d_in[2];
    const float* ba   = (const float*)d_in[3];
    const float* wb   = (const float*)d_in[4];
    const float* bbv  = (const float*)d_in[5];
    const float* in_w = (const float*)d_in[6];
    const float* in_b = (const float*)d_in[7];
    const float* w1   = (const float*)d_in[8];
    const float* b1   = (const float*)d_in[9];
    const float* g1   = (const float*)d_in[10];
    const float* be1  = (const float*)d_in[11];
    const float* w2   = (const float*)d_in[12];
    const float* b2   = (const float*)d_in[13];
    const float* g2   = (const float*)d_in[14];
    const float* be2  = (const float*)d_in[15];
    const float* w3   = (const float*)d_in[16];
    const float* b3   = (const float*)d_in[17];
    const float* wq   = (const float*)d_in[18];
    const float* bq   = (const float*)d_in[19];
    const float* wk   = (const float*)d_in[20];
    const float* bk   = (const float*)d_in[21];
    const float* wv   = (const float*)d_in[22];
    const float* bv   = (const float*)d_in[23];
    const float* wo   = (const float*)d_in[24];
    const float* bo   = (const float*)d_in[25];
    const float* rescale = (const float*)d_in[26];

    float* ws = (float*)d_ws;
    const size_t P64 = (size_t)4 * 64 * NPX;   // 4.19M floats

    float* xm   = ws;                          // fp32, live to end
    float* regA = ws + P64;                    // h1n (bf16), later q (bf16)
    float* regB = ws + 2 * P64;                // h2n (bf16), later k|v (bf16)
    float* regC = ws + 3 * P64;                // y (bf16), only needs P64/2
    float* gram = ws + 3 * P64 + P64 / 2;      // 4096
    float* nsq  = gram + 4096;                 // 512
    float* M    = nsq + 512;                   // 16384

    bf16* h1n = (bf16*)regA;
    bf16* h2n = (bf16*)regB;
    bf16* y   = (bf16*)regC;
    bf16* q   = (bf16*)regA;                   // reuse after h1n dead
    bf16* kk  = (bf16*)regB;                   // reuse after h2n dead
    bf16* vv  = (bf16*)(regB + P64 / 2);

    dim3 blk(256), grd(256);
    hipMemsetAsync(gram, 0, (4096 + 512) * sizeof(float), stream);
    k_fused_y<<<grd, blk, 0, stream>>>(x, sem, wa, ba, wb, bbv, in_w, in_b, y);
    k_mlp1<<<grd, blk, 0, stream>>>(x, w1, b1, g1, be1, h1n);
    k_mlp2<<<grd, blk, 0, stream>>>(h1n, w2, b2, g2, be2, h2n);
    k_mlp3q<<<grd, blk, 0, stream>>>(h2n, w3, b3, wq, bq, xm, q);
    k_kv<<<grd, blk, 0, stream>>>(y, wk, bk, wv, bv, kk, vv);
    k_gramnorm<<<grd, blk, 0, stream>>>(q, kk, gram, nsq);
    k_attnM<<<dim3(4), blk, 0, stream>>>(gram, nsq, rescale, wo, M);
    k_out<<<grd, blk, 0, stream>>>(vv, xm, M, bo, (float*)d_out);
}

// Round 3
// 194.098 us; speedup vs baseline: 3.2750x; 3.2750x over previous
//
#include <hip/hip_runtime.h>
#include <hip/hip_bf16.h>

#define NPX 16384
using bf16 = __hip_bfloat16;
typedef __attribute__((ext_vector_type(8))) short short8;
typedef __attribute__((ext_vector_type(4))) short short4v;
typedef __attribute__((ext_vector_type(4))) float f32x4;

#define DEV static __device__ __forceinline__

DEV float lrelu(float v) { return v >= 0.f ? v : 0.01f * v; }
DEV short f2b(float f) { __hip_bfloat16 h = __float2bfloat16(f); return *reinterpret_cast<short*>(&h); }
DEV float b2f(short s) { __hip_bfloat16 h; *reinterpret_cast<short*>(&h) = s; return __bfloat162float(h); }
DEV f32x4 mfma16(short8 a, short8 b, f32x4 c) {
    return __builtin_amdgcn_mfma_f32_16x16x32_bf16(a, b, c, 0, 0, 0);
}

// ---------------------------------------------------------------------------
// Core GEMM: D[px][e] += sum_k A[px][k] * WT[e][k], px-tile 32 per wave
// (2 m-tiles), NT n-tiles of 16. A: bf16 rows pitch `pitch`; WT: bf16 [e][K].
// A-frag:  A[m=lane&15][k=(lane>>4)*8 + j]  (16B contiguous)
// B-frag:  B[k=(lane>>4)*8+j][n=lane&15] = WT[(lane&15)][k]  (16B contiguous)
// D:       col=lane&15, row=(lane>>4)*4+reg   [verified m89/m91]
// ---------------------------------------------------------------------------
template<int K, int NT>
DEV void gemm(const short* __restrict__ A, int px0, int pitch,
              const short* __restrict__ WT, f32x4 acc[2][NT])
{
    int lane = threadIdx.x & 63;
    int ln = lane & 15, q8 = (lane >> 4) * 8;
    const short* a0p = A + (size_t)(px0 + ln) * pitch + q8;
    const short* a1p = a0p + 16 * pitch;
    const short* bp  = WT + ln * K + q8;
#pragma unroll
    for (int c0 = 0; c0 < K; c0 += 32) {
        short8 a0 = *(const short8*)(a0p + c0);
        short8 a1 = *(const short8*)(a1p + c0);
#pragma unroll
        for (int t = 0; t < NT; ++t) {
            short8 b = *(const short8*)(bp + (size_t)t * 16 * K + c0);
            acc[0][t] = mfma16(a0, b, acc[0][t]);
            acc[1][t] = mfma16(a1, b, acc[1][t]);
        }
    }
}

template<int NT>
DEV void acc_bias(f32x4 acc[2][NT], const float* __restrict__ bias)
{
    int ln = threadIdx.x & 15;
#pragma unroll
    for (int t = 0; t < NT; ++t) {
        float bv = bias[t * 16 + ln];
        f32x4 v = {bv, bv, bv, bv};
        acc[0][t] = v; acc[1][t] = v;
    }
}

template<int NT>
DEV void acc_zero(f32x4 acc[2][NT])
{
    f32x4 z = {0.f, 0.f, 0.f, 0.f};
#pragma unroll
    for (int t = 0; t < NT; ++t) { acc[0][t] = z; acc[1][t] = z; }
}

// write D tiles (bf16) into LDS [px][PITCH]
template<int NT, int PITCH>
DEV void dstore(f32x4 acc[2][NT], short* sD, int px0)
{
    int lane = threadIdx.x & 63;
    int ln = lane & 15, r0 = (lane >> 4) * 4;
#pragma unroll
    for (int m = 0; m < 2; ++m)
#pragma unroll
        for (int t = 0; t < NT; ++t)
#pragma unroll
            for (int r = 0; r < 4; ++r)
                sD[(px0 + m * 16 + r0 + r) * PITCH + t * 16 + ln] = f2b(acc[m][t][r]);
}

// cooperative coalesced copy LDS[128][PITCH] (bf16, CW valid cols) -> global
template<int CW, int PITCH>
DEV void copyout(const short* sD, short* __restrict__ dst)
{
    int tid = threadIdx.x;
#pragma unroll
    for (int j = 0; j < (128 * CW) / 2048; ++j) {
        int idx = j * 2048 + tid * 8;
        int px = idx / CW, c = idx % CW;
        short8 v = *(const short8*)(&sD[px * PITCH + c]);
        *reinterpret_cast<short8*>(dst + (size_t)px * CW + c) = v;
    }
}

// stage x (fp32 [64][NPX] slice) -> LDS [128][72] bf16 pixel-major
DEV void stage_x64(const float* __restrict__ xb, int nbase, short* sA)
{
    int tid = threadIdx.x;
#pragma unroll
    for (int it = 0; it < 8; ++it) {
        int item = it * 256 + tid;
        int n = item & 127, cg = item >> 7;   // cg 0..15
        float v0 = xb[(cg * 4 + 0) * NPX + nbase + n];
        float v1 = xb[(cg * 4 + 1) * NPX + nbase + n];
        float v2 = xb[(cg * 4 + 2) * NPX + nbase + n];
        float v3 = xb[(cg * 4 + 3) * NPX + nbase + n];
        short4v pk = {f2b(v0), f2b(v1), f2b(v2), f2b(v3)};
        *reinterpret_cast<short4v*>(&sA[n * 72 + cg * 4]) = pk;
    }
}

// ---------------------------------------------------------------------------
// k_prep: build transposed bf16 weights WT[e][k]
// layout: wab 0 | in_w 4096 | w1 8192 | w2 16384 | w3 32768 | wq 40960 | wkv 45056
// ---------------------------------------------------------------------------
__global__ __launch_bounds__(256) void k_prep(const float* __restrict__ wa,
                                              const float* __restrict__ wb,
                                              const float* __restrict__ in_w,
                                              const float* __restrict__ w1,
                                              const float* __restrict__ w2,
                                              const float* __restrict__ w3,
                                              const float* __restrict__ wq,
                                              const float* __restrict__ wk,
                                              const float* __restrict__ wv,
                                              short* __restrict__ wt)
{
    int idx = blockIdx.x * 256 + threadIdx.x;
    float v;
    if (idx < 4096) {
        int j = idx >> 6, c = idx & 63;
        v = (j < 4) ? wa[c * 4 + j] : wb[((j - 4) / 3) * 192 + c * 3 + ((j - 4) % 3)];
    } else if (idx < 8192) {
        int i = idx - 4096; int e = i >> 6, k = i & 63; v = in_w[k * 64 + e];
    } else if (idx < 16384) {
        int i = idx - 8192; int e = i >> 6, k = i & 63; v = w1[k * 128 + e];
    } else if (idx < 32768) {
        int i = idx - 16384; int e = i >> 7, k = i & 127; v = w2[k * 128 + e];
    } else if (idx < 40960) {
        int i = idx - 32768; int e = i >> 7, k = i & 127; v = w3[k * 64 + e];
    } else if (idx < 45056) {
        int i = idx - 40960; int e = i >> 6, k = i & 63; v = wq[k * 64 + e];
    } else {
        int i = idx - 45056; int e = i >> 6, k = i & 63;
        v = (e < 64) ? wk[k * 64 + e] : wv[k * 64 + (e - 64)];
    }
    wt[idx] = f2b(v);
}

// ---------------------------------------------------------------------------
// k_fyk: x,sem -> feat -> y -> kv[n][128] bf16  (3 chained GEMMs)
// ---------------------------------------------------------------------------
__global__ __launch_bounds__(256) void k_fyk(const float* __restrict__ x,
                                             const float* __restrict__ sem,
                                             const float* __restrict__ ba,
                                             const float* __restrict__ bbv,
                                             const float* __restrict__ in_b,
                                             const float* __restrict__ bk,
                                             const float* __restrict__ bv,
                                             const short* __restrict__ wt,
                                             short* __restrict__ kvout)
{
    __shared__ short sA[128 * 136];
    int tid = threadIdx.x, w = tid >> 6, lane = tid & 63;
    int ln = lane & 15, qd = lane >> 4;
    int pxb = blockIdx.x * 128;
    int b = pxb >> 14, nbase = pxb & (NPX - 1);
    const float* xb = x + (size_t)b * 64 * NPX;
    int px0 = w * 32;

    stage_x64(xb, nbase, sA);
    __syncthreads();

    f32x4 a1[2][4];
    acc_zero<4>(a1);
    gemm<64, 4>(sA, px0, 72, wt + 0, a1);
    __syncthreads();
    // feat epilogue: mask by relu(sem[class]) + bias -> LDS pitch 72
#pragma unroll
    for (int m = 0; m < 2; ++m)
#pragma unroll
        for (int t = 0; t < 4; ++t) {
            int j = t * 16 + ln;
            int cls = (j < 4) ? 0 : 1 + (j - 4) / 3;
            float bias = (j < 4) ? ba[j] : bbv[j - 4];
            int rg = nbase + px0 + m * 16 + qd * 4;
            f32x4 sm4 = *(const f32x4*)(sem + ((size_t)b * 21 + cls) * NPX + rg);
#pragma unroll
            for (int r = 0; r < 4; ++r)
                sA[(px0 + m * 16 + qd * 4 + r) * 72 + j] =
                    f2b(fmaxf(sm4[r], 0.f) * a1[m][t][r] + bias);
        }
    __syncthreads();

    f32x4 a2[2][4];
    acc_bias<4>(a2, in_b);
    gemm<64, 4>(sA, px0, 72, wt + 4096, a2);
    __syncthreads();
    dstore<4, 72>(a2, sA, px0);
    __syncthreads();

    f32x4 a3[2][8];
    {
        int lnn = tid & 15;
#pragma unroll
        for (int t = 0; t < 8; ++t) {
            float bvv = (t < 4) ? bk[t * 16 + lnn] : bv[(t - 4) * 16 + lnn];
            f32x4 vv = {bvv, bvv, bvv, bvv};
            a3[0][t] = vv; a3[1][t] = vv;
        }
    }
    gemm<64, 8>(sA, px0, 72, wt + 45056, a3);
    __syncthreads();
    dstore<8, 136>(a3, sA, px0);
    __syncthreads();
    copyout<128, 136>(sA, kvout + (size_t)pxb * 128);
}

// ---------------------------------------------------------------------------
// LN pass over LDS D [128][136] bf16: stats then apply (+lrelu); write back to
// LDS (gout==nullptr) or to global pixel-major rows.
// ---------------------------------------------------------------------------
DEV void ln_pass(short* sD, float* s_mean, float* s_rs,
                 const float* __restrict__ g, const float* __restrict__ be,
                 short* __restrict__ gout)
{
    int tid = threadIdx.x;
    int px = tid >> 1, half = (tid & 1) * 64;
    float s = 0.f, ss = 0.f;
#pragma unroll
    for (int j = 0; j < 8; ++j) {
        short8 v8 = *(const short8*)(&sD[px * 136 + half + j * 8]);
#pragma unroll
        for (int e = 0; e < 8; ++e) { float f = b2f(v8[e]); s += f; ss += f * f; }
    }
    s += __shfl_xor(s, 1); ss += __shfl_xor(ss, 1);
    if ((tid & 1) == 0) {
        float m = s * (1.f / 128.f);
        float var = ss * (1.f / 128.f) - m * m;
        s_mean[px] = m; s_rs[px] = rsqrtf(var + 1e-5f);
    }
    __syncthreads();
#pragma unroll
    for (int j = 0; j < 8; ++j) {
        int idx = j * 2048 + tid * 8;
        int p2 = idx >> 7, c = idx & 127;
        short8 v8 = *(const short8*)(&sD[p2 * 136 + c]);
        float m = s_mean[p2], r = s_rs[p2];
        f32x4 g0 = *(const f32x4*)(g + c), g1v = *(const f32x4*)(g + c + 4);
        f32x4 b0 = *(const f32x4*)(be + c), b1v = *(const f32x4*)(be + c + 4);
        short8 o;
#pragma unroll
        for (int e = 0; e < 8; ++e) {
            float gg = (e < 4) ? g0[e] : g1v[e - 4];
            float bb = (e < 4) ? b0[e] : b1v[e - 4];
            o[e] = f2b(lrelu((b2f(v8[e]) - m) * r * gg + bb));
        }
        if (gout) *reinterpret_cast<short8*>(gout + (size_t)idx) = o;
        else      *reinterpret_cast<short8*>(&sD[p2 * 136 + c]) = o;
    }
}

// ---------------------------------------------------------------------------
// k_m12: x -> h1=lrelu(LN(x@w1+b1)) -> h2=lrelu(LN(h1@w2+b2))  [n][128] bf16
// ---------------------------------------------------------------------------
__global__ __launch_bounds__(256) void k_m12(const float* __restrict__ x,
                                             const float* __restrict__ b1,
                                             const float* __restrict__ g1,
                                             const float* __restrict__ be1,
                                             const float* __restrict__ b2,
                                             const float* __restrict__ g2,
                                             const float* __restrict__ be2,
                                             const short* __restrict__ wt,
                                             short* __restrict__ h2out)
{
    __shared__ short sA[128 * 136];
    __shared__ float s_mean[128], s_rs[128];
    int tid = threadIdx.x, w = tid >> 6;
    int pxb = blockIdx.x * 128;
    int b = pxb >> 14, nbase = pxb & (NPX - 1);
    const float* xb = x + (size_t)b * 64 * NPX;
    int px0 = w * 32;

    stage_x64(xb, nbase, sA);
    __syncthreads();

    f32x4 acc[2][8];
    acc_bias<8>(acc, b1);
    gemm<64, 8>(sA, px0, 72, wt + 8192, acc);
    __syncthreads();
    dstore<8, 136>(acc, sA, px0);
    __syncthreads();
    ln_pass(sA, s_mean, s_rs, g1, be1, nullptr);
    __syncthreads();

    acc_bias<8>(acc, b2);
    gemm<128, 8>(sA, px0, 136, wt + 16384, acc);
    __syncthreads();
    dstore<8, 136>(acc, sA, px0);
    __syncthreads();
    ln_pass(sA, s_mean, s_rs, g2, be2, h2out + (size_t)pxb * 128);
}

// ---------------------------------------------------------------------------
// k_m3q: h2 -> xm = h2@w3+b3 (bf16 out, residual) -> q = xm@wq+bq
// ---------------------------------------------------------------------------
__global__ __launch_bounds__(256) void k_m3q(const short* __restrict__ h2,
                                             const float* __restrict__ b3,
                                             const float* __restrict__ bq,
                                             const short* __restrict__ wt,
                                             short* __restrict__ xm,
                                             short* __restrict__ q)
{
    __shared__ short sA[128 * 72];
    int tid = threadIdx.x, w = tid >> 6;
    int pxb = blockIdx.x * 128;
    int px0 = w * 32;

    f32x4 acc[2][4];
    acc_bias<4>(acc, b3);
    gemm<128, 4>(h2 + (size_t)pxb * 128, px0, 128, wt + 32768, acc);
    dstore<4, 72>(acc, sA, px0);
    __syncthreads();
    copyout<64, 72>(sA, xm + (size_t)pxb * 64);

    f32x4 a2[2][4];
    acc_bias<4>(a2, bq);
    gemm<64, 4>(sA, px0, 72, wt + 40960, a2);
    __syncthreads();
    dstore<4, 72>(a2, sA, px0);
    __syncthreads();
    copyout<64, 72>(sA, q + (size_t)pxb * 64);
}

// ---------------------------------------------------------------------------
// k_gram: gram[bh][d][e] += q^T k over pixel chunks; nsq via qq/kk diagonals.
// grid 256 = 16 (b,h) x 16 chunks of 1024 px; each wave owns 256 px.
// ---------------------------------------------------------------------------
__global__ __launch_bounds__(256) void k_gram(const short* __restrict__ q,
                                              const short* __restrict__ kv,
                                              float* __restrict__ gram,
                                              float* __restrict__ nsq)
{
    __shared__ short sQ[4][16 * 264];
    __shared__ short sK[4][16 * 264];
    int tid = threadIdx.x, w = tid >> 6, lane = tid & 63;
    int ln = lane & 15, q8 = (lane >> 4) * 8, qd = lane >> 4;
    int bh = blockIdx.x >> 4;
    int b = bh >> 2, h = bh & 3;
    int nb = (blockIdx.x & 15) * 1024 + w * 256;
    size_t pxg = (size_t)b * NPX + nb;

#pragma unroll
    for (int it = 0; it < 8; ++it) {
        int item = it * 64 + lane;
        int px = item & 255, dc = item >> 8;
        short8 qv = *(const short8*)(q + (pxg + px) * 64 + h * 16 + dc * 8);
        short8 kvv = *(const short8*)(kv + (pxg + px) * 128 + h * 16 + dc * 8);
#pragma unroll
        for (int jj = 0; jj < 8; ++jj) {
            sQ[w][(dc * 8 + jj) * 264 + px] = qv[jj];
            sK[w][(dc * 8 + jj) * 264 + px] = kvv[jj];
        }
    }
    __syncthreads();

    f32x4 aqk = {0,0,0,0}, aqq = {0,0,0,0}, akk = {0,0,0,0};
#pragma unroll
    for (int s = 0; s < 8; ++s) {
        short8 a = *(const short8*)(&sQ[w][ln * 264 + s * 32 + q8]);
        short8 bf = *(const short8*)(&sK[w][ln * 264 + s * 32 + q8]);
        aqk = mfma16(a, bf, aqk);
        aqq = mfma16(a, a, aqq);
        akk = mfma16(bf, bf, akk);
    }
    int e = ln;
#pragma unroll
    for (int r = 0; r < 4; ++r) {
        int d = qd * 4 + r;
        atomicAdd(&gram[bh * 256 + d * 16 + e], aqk[r]);
        if (e == d) {
            atomicAdd(&nsq[bh * 16 + d], aqq[r]);
            atomicAdd(&nsq[256 + bh * 16 + d], akk[r]);
        }
    }
}

// ---------------------------------------------------------------------------
// k_attnM: softmax + fold wo -> MT[b][cc][he] bf16
// ---------------------------------------------------------------------------
__global__ __launch_bounds__(256) void k_attnM(const float* __restrict__ gram,
                                               const float* __restrict__ nsq,
                                               const float* __restrict__ rescale,
                                               const float* __restrict__ wo,
                                               short* __restrict__ MT)
{
    __shared__ float s_at[1024];
    int b = blockIdx.x, tid = threadIdx.x;
    if (tid < 64) {
        int h = tid >> 4, d = tid & 15;
        float nq = sqrtf(nsq[b * 64 + h * 16 + d]) + 1e-8f;
        float rsc = rescale[h];
        float lg[16];
#pragma unroll
        for (int e = 0; e < 16; ++e) {
            float nk = sqrtf(nsq[256 + b * 64 + h * 16 + e]) + 1e-8f;
            lg[e] = rsc * gram[b * 1024 + h * 256 + d * 16 + e] / (nq * nk);
        }
        float m = lg[0];
#pragma unroll
        for (int e = 1; e < 16; ++e) m = fmaxf(m, lg[e]);
        float ssum = 0.f;
#pragma unroll
        for (int e = 0; e < 16; ++e) { lg[e] = expf(lg[e] - m); ssum += lg[e]; }
        float inv = 1.f / ssum;
#pragma unroll
        for (int e = 0; e < 16; ++e) s_at[h * 256 + d * 16 + e] = lg[e] * inv;
    }
    __syncthreads();
    int he = tid >> 2, h = he >> 4, e = he & 15;
    int cc0 = (tid & 3) * 16;
#pragma unroll
    for (int cx = 0; cx < 16; ++cx) {
        int cc = cc0 + cx;
        float s = 0.f;
#pragma unroll
        for (int d = 0; d < 16; ++d)
            s = fmaf(s_at[h * 256 + d * 16 + e], wo[(h * 16 + d) * 64 + cc], s);
        MT[b * 4096 + cc * 64 + he] = f2b(s);
    }
}

// ---------------------------------------------------------------------------
// k_out: out[b][c][n] = v@M + bo + xm   (fp32, channel-major output)
// ---------------------------------------------------------------------------
__global__ __launch_bounds__(256) void k_out(const short* __restrict__ kv,
                                             const short* __restrict__ xm,
                                             const short* __restrict__ MT,
                                             const float* __restrict__ bo,
                                             float* __restrict__ out)
{
    int tid = threadIdx.x, w = tid >> 6, lane = tid & 63;
    int ln = lane & 15, qd = lane >> 4;
    int pxb = blockIdx.x * 128;
    int b = pxb >> 14, nbase = pxb & (NPX - 1);
    int px0 = w * 32;

    f32x4 acc[2][4];
    acc_bias<4>(acc, bo);
    gemm<64, 4>(kv + (size_t)pxb * 128 + 64, px0, 128, MT + b * 4096, acc);

#pragma unroll
    for (int m = 0; m < 2; ++m)
#pragma unroll
        for (int t = 0; t < 4; ++t) {
            int c = t * 16 + ln;
            int n = nbase + px0 + m * 16 + qd * 4;
            const short* xp = xm + ((size_t)pxb + px0 + m * 16 + qd * 4) * 64 + c;
            f32x4 v;
#pragma unroll
            for (int r = 0; r < 4; ++r) v[r] = acc[m][t][r] + b2f(xp[r * 64]);
            *reinterpret_cast<f32x4*>(out + ((size_t)b * 64 + c) * NPX + n) = v;
        }
}

// ---------------------------------------------------------------------------
extern "C" void kernel_launch(void* const* d_in, const int* in_sizes, int n_in,
                              void* d_out, int out_size, void* d_ws, size_t ws_size,
                              hipStream_t stream)
{
    const float* x    = (const float*)d_in[0];
    const float* sem  = (const float*)d_in[1];
    const float* wa   = (const float*)d_in[2];
    const float* ba   = (const float*)d_in[3];
    const float* wb   = (const float*)d_in[4];
    const float* bbv  = (const float*)d_in[5];
    const float* in_w = (const float*)d_in[6];
    const float* in_b = (const float*)d_in[7];
    const float* w1   = (const float*)d_in[8];
    const float* b1   = (const float*)d_in[9];
    const float* g1   = (const float*)d_in[10];
    const float* be1  = (const float*)d_in[11];
    const float* w2   = (const float*)d_in[12];
    const float* b2   = (const float*)d_in[13];
    const float* g2   = (const float*)d_in[14];
    const float* be2  = (const float*)d_in[15];
    const float* w3   = (const float*)d_in[16];
    const float* b3   = (const float*)d_in[17];
    const float* wq   = (const float*)d_in[18];
    const float* bq   = (const float*)d_in[19];
    const float* wk   = (const float*)d_in[20];
    const float* bk   = (const float*)d_in[21];
    const float* wv   = (const float*)d_in[22];
    const float* bv   = (const float*)d_in[23];
    const float* wo   = (const float*)d_in[24];
    const float* bo   = (const float*)d_in[25];
    const float* rescale = (const float*)d_in[26];

    char* wsb = (char*)d_ws;
    short* wt   = (short*)wsb;                               // 53248 shorts
    short* kv   = (short*)(wsb + (1 << 20));                 // 65536*128 shorts = 16 MB
    short* h2   = (short*)(wsb + (1 << 20) + (16u << 20));   // 16 MB
    short* xmp  = (short*)(wsb + (1 << 20) + (32u << 20));   // 8 MB
    short* qp   = (short*)(wsb + (1 << 20) + (40u << 20));   // 8 MB
    float* gram = (float*)(wsb + (1 << 20) + (48u << 20));   // 4096 f32
    float* nsq  = gram + 4096;                               // 512 f32
    short* MT   = (short*)(nsq + 512);                       // 16384 shorts

    dim3 blk(256);
    k_prep<<<dim3(208), blk, 0, stream>>>(wa, wb, in_w, w1, w2, w3, wq, wk, wv, wt);
    hipMemsetAsync(gram, 0, (4096 + 512) * sizeof(float), stream);
    k_fyk<<<dim3(512), blk, 0, stream>>>(x, sem, ba, bbv, in_b, bk, bv, wt, kv);
    k_m12<<<dim3(512), blk, 0, stream>>>(x, b1, g1, be1, b2, g2, be2, wt, h2);
    k_m3q<<<dim3(512), blk, 0, stream>>>(h2, b3, bq, wt, xmp, qp);
    k_gram<<<dim3(256), blk, 0, stream>>>(qp, kv, gram, nsq);
    k_attnM<<<dim3(4), blk, 0, stream>>>(gram, nsq, rescale, wo, MT);
    k_out<<<dim3(512), blk, 0, stream>>>(kv, xmp, MT, bo, (float*)d_out);
}